// Round 9
// baseline (1873.794 us; speedup 1.0000x reference)
//
#include <hip/hip_runtime.h>
#include <hip/hip_fp16.h>

#define CCH  64
#define NBLK 128        // phase-A partition blocks
#define HBSZ 128        // dst nodes per half-bucket (= prop block)

// ---------------- Phase A: counting sort of edges by 128-node dst block ----------------

__global__ void countA(const int* __restrict__ dst, int* __restrict__ cntmat,
                       int E, int chunk, int NHB) {
    __shared__ int h[784];
    int t = threadIdx.x, blk = blockIdx.x;
    for (int i = t; i < NHB; i += 256) h[i] = 0;
    __syncthreads();
    int e0 = blk * chunk, e1 = min(e0 + chunk, E);
    for (int e = e0 + t; e < e1; e += 256) atomicAdd(&h[dst[e] >> 7], 1);
    __syncthreads();
    for (int i = t; i < NHB; i += 256) cntmat[i * NBLK + blk] = h[i];
}

// Two-level exclusive scan (1024 elems / block)
__global__ void scan1(const int* __restrict__ cnt, int* __restrict__ part,
                      int* __restrict__ bsum, int N) {
    __shared__ int s[256];
    int t = threadIdx.x;
    int base = blockIdx.x * 1024 + t * 4;
    int v0 = (base + 0 < N) ? cnt[base + 0] : 0;
    int v1 = (base + 1 < N) ? cnt[base + 1] : 0;
    int v2 = (base + 2 < N) ? cnt[base + 2] : 0;
    int v3 = (base + 3 < N) ? cnt[base + 3] : 0;
    s[t] = v0 + v1 + v2 + v3;
    __syncthreads();
    for (int off = 1; off < 256; off <<= 1) {
        int xx = (t >= off) ? s[t - off] : 0;
        __syncthreads();
        s[t] += xx;
        __syncthreads();
    }
    int excl = (t == 0) ? 0 : s[t - 1];
    if (t == 255) bsum[blockIdx.x] = s[255];
    if (base + 0 < N) part[base + 0] = excl;
    if (base + 1 < N) part[base + 1] = excl + v0;
    if (base + 2 < N) part[base + 2] = excl + v0 + v1;
    if (base + 3 < N) part[base + 3] = excl + v0 + v1 + v2;
}

__global__ void scan2(int* __restrict__ bsum, int NB) {
    __shared__ int s[256];
    int t = threadIdx.x;
    int base = t * 4;
    int v0 = (base + 0 < NB) ? bsum[base + 0] : 0;
    int v1 = (base + 1 < NB) ? bsum[base + 1] : 0;
    int v2 = (base + 2 < NB) ? bsum[base + 2] : 0;
    int v3 = (base + 3 < NB) ? bsum[base + 3] : 0;
    s[t] = v0 + v1 + v2 + v3;
    __syncthreads();
    for (int off = 1; off < 256; off <<= 1) {
        int xx = (t >= off) ? s[t - off] : 0;
        __syncthreads();
        s[t] += xx;
        __syncthreads();
    }
    int excl = (t == 0) ? 0 : s[t - 1];
    if (base + 0 < NB) bsum[base + 0] = excl;
    if (base + 1 < NB) bsum[base + 1] = excl + v0;
    if (base + 2 < NB) bsum[base + 2] = excl + v0 + v1;
    if (base + 3 < NB) bsum[base + 3] = excl + v0 + v1 + v2;
}

// partition: write (src<<7 | dst&127) into per-(hb,blk) exclusive ranges (~10-edge runs)
__global__ void partA(const int* __restrict__ src, const int* __restrict__ dst,
                      const int* __restrict__ part, const int* __restrict__ bsum,
                      unsigned* __restrict__ brec, int E, int chunk, int NHB) {
    __shared__ int cur[784];
    int t = threadIdx.x, blk = blockIdx.x;
    for (int i = t; i < NHB; i += 256) {
        int idx = i * NBLK + blk;
        cur[i] = part[idx] + bsum[idx >> 10];
    }
    __syncthreads();
    int e0 = blk * chunk, e1 = min(e0 + chunk, E);
    for (int e = e0 + t; e < e1; e += 256) {
        int s = src[e], d = dst[e];
        int pos = atomicAdd(&cur[d >> 7], 1);
        brec[pos] = ((unsigned)s << 7) | (unsigned)(d & 127);
    }
}

// ---------------- Phase B: per-half-bucket finalize ----------------
// 1 block = 128 dst nodes. (a) degree histogram -> dinv/dinv2, (b) reorders its
// ~1280 edge recs by SRC BAND (13 bands of 8192 nodes) into brec2 so the prop
// sweep's hot src window is L2-resident, (c) fused tohalf u0 = fp16(dinv*x).
__global__ void buildB(const unsigned* __restrict__ brec, const int* __restrict__ part,
                       const int* __restrict__ bsum, unsigned* __restrict__ brec2,
                       float* __restrict__ dinv, float* __restrict__ dinv2,
                       const float* __restrict__ x, __half* __restrict__ xh,
                       int N, int NHB, int E) {
    __shared__ int bandcur[16];
    __shared__ int bandh[16];
    __shared__ int degh[128];
    __shared__ float sdinv[128];
    int t = threadIdx.x, hb = blockIdx.x;
    int e0 = part[hb * NBLK] + bsum[(hb * NBLK) >> 10];
    int e1 = (hb + 1 < NHB) ? part[(hb + 1) * NBLK] + bsum[((hb + 1) * NBLK) >> 10] : E;
    if (t < 16) bandh[t] = 0;
    if (t < 128) degh[t] = 0;
    __syncthreads();
    for (int i = e0 + t; i < e1; i += 256) {
        unsigned r = brec[i];
        atomicAdd(&bandh[r >> 20], 1);      // band = src>>13 = rec>>20
        atomicAdd(&degh[r & 127u], 1);
    }
    __syncthreads();
    if (t == 0) {
        int s = e0;
        for (int b = 0; b < 13; ++b) { bandcur[b] = s; s += bandh[b]; }
    }
    __syncthreads();
    for (int i = e0 + t; i < e1; i += 256) {
        unsigned r = brec[i];
        int pos = atomicAdd(&bandcur[r >> 20], 1);
        brec2[pos] = r;                     // block-owned contiguous writes
    }
    float di = 0.f;
    if (t < 128) {
        int node = hb * 128 + t;
        if (node < N) {
            float dp1 = (float)degh[t] + 1.0f;   // degree incl. self-loop
            di = rsqrtf(dp1);
            dinv[node]  = di;
            dinv2[node] = 1.0f / dp1;
        }
        sdinv[t] = di;
    }
    __syncthreads();
    // fused tohalf: 128 nodes x 64 ch, 8 floats per thread-iter (coalesced)
    for (int i = t; i < 1024; i += 256) {
        int nl = i >> 3;
        int node = hb * 128 + nl;
        if (node < N) {
            float d = sdinv[nl];
            size_t base = (size_t)node * 64 + (size_t)(i & 7) * 8;
            float4 a = *(const float4*)&x[base];
            float4 c = *(const float4*)&x[base + 4];
            float4 o;
            __half2* op = (__half2*)&o;
            op[0] = __float22half2_rn(make_float2(d * a.x, d * a.y));
            op[1] = __float22half2_rn(make_float2(d * a.z, d * a.w));
            op[2] = __float22half2_rn(make_float2(d * c.x, d * c.y));
            op[3] = __float22half2_rn(make_float2(d * c.z, d * c.w));
            *(float4*)&xh[base] = o;
        }
    }
}

// ---------------- propagation: LDS-accumulate, band-ordered sweep ----------------
// u_out[i] = scale[i] * (u[i] + sum_j u[j]).  Block = 128 dst nodes, fp32 acc
// in 32 KB LDS (lane=ch -> 2-way bank alias, free).  Edge recs are wave-uniform
// SCALAR loads (readfirstlane-forced uniform base -> s_load); u-row gathers are
// 128B coalesced ushort loads batched 8-deep (8 in flight/wave); accumulate =
// one ds_add_f32 per edge.  All blocks sweep src bands 0..12 in order -> the
// GPU-wide hot src window is ~1-2 MB -> L2-resident (R8 lesson: the wall is
// requests x latency / per-CU concurrency; this cuts latency ~2.5x).
__global__ void __launch_bounds__(256, 4)
prop_kernel(const __half* __restrict__ u, __half* __restrict__ out,
            const unsigned* __restrict__ brec2, const int* __restrict__ part,
            const int* __restrict__ bsum, const float* __restrict__ scale,
            int N, int NHB, int E) {
    __shared__ float acc[128 * 64];     // 32 KB
    int t = threadIdx.x, hb = blockIdx.x;
    int wv = __builtin_amdgcn_readfirstlane(t >> 6);   // provably wave-uniform
    int lane = t & 63;
    for (int i = t; i < 2048; i += 256)
        ((float4*)acc)[i] = make_float4(0.f, 0.f, 0.f, 0.f);
    __syncthreads();
    int e0 = part[hb * NBLK] + bsum[(hb * NBLK) >> 10];
    int e1 = (hb + 1 < NHB) ? part[(hb + 1) * NBLK] + bsum[((hb + 1) * NBLK) >> 10] : E;

    for (int base = e0 + wv * 64; base < e1; base += 256) {
        int n = min(64, e1 - base);
        int tt = 0;
        for (; tt + 8 <= n; tt += 8) {
            unsigned rr[8];
            #pragma unroll
            for (int k = 0; k < 8; ++k) rr[k] = brec2[base + tt + k];  // s_load
            __half vv[8];
            #pragma unroll
            for (int k = 0; k < 8; ++k)
                vv[k] = u[(size_t)(rr[k] >> 7) * 64 + lane];           // 8 in flight
            #pragma unroll
            for (int k = 0; k < 8; ++k)
                atomicAdd(&acc[(rr[k] & 127u) * 64 + lane], __half2float(vv[k]));
        }
        for (; tt < n; ++tt) {
            unsigned r = brec2[base + tt];
            __half v = u[(size_t)(r >> 7) * 64 + lane];
            atomicAdd(&acc[(r & 127u) * 64 + lane], __half2float(v));
        }
    }
    __syncthreads();
    // writeout: wave wv handles nodes [wv*32, wv*32+32)
    for (int i = 0; i < 32; ++i) {
        int nl = wv * 32 + i;
        int node = hb * 128 + nl;
        if (node < N) {
            float a  = acc[nl * 64 + lane];
            float sv = __half2float(u[(size_t)node * 64 + lane]);  // self term
            out[(size_t)node * 64 + lane] = __float2half(scale[node] * (a + sv));
        }
    }
}

// ---------------- final: out = 2x + h @ W^T + b - x_pre ----------------
__global__ void __launch_bounds__(256, 2)
final_kernel(const __half* __restrict__ h, const float* __restrict__ x,
             const float* __restrict__ xp, const float* __restrict__ W,
             const float* __restrict__ b, float* __restrict__ out, int N) {
    __shared__ __align__(16) float ht[64 * 68];
    __shared__ __align__(16) float Wt[64 * 68];
    int t = threadIdx.x;
    int nodeBase = blockIdx.x * 64;

    for (int i = t; i < 1024; i += 256) {
        int c  = i >> 4;
        int k4 = i & 15;
        float4 w4 = ((const float4*)W)[i];
        Wt[(k4 * 4 + 0) * 68 + c] = w4.x;
        Wt[(k4 * 4 + 1) * 68 + c] = w4.y;
        Wt[(k4 * 4 + 2) * 68 + c] = w4.z;
        Wt[(k4 * 4 + 3) * 68 + c] = w4.w;
    }
    for (int i = t; i < 512; i += 256) {
        int n  = i >> 3;
        int k8 = i & 7;
        int node = nodeBase + n;
        float4 hv = (node < N) ? ((const float4*)h)[node * 8 + k8]
                               : make_float4(0.f, 0.f, 0.f, 0.f);
        __half2* hp = (__half2*)&hv;
        #pragma unroll
        for (int j = 0; j < 4; ++j) {
            float2 f = __half22float2(hp[j]);
            ht[(k8 * 8 + 2 * j)     * 68 + n] = f.x;
            ht[(k8 * 8 + 2 * j + 1) * 68 + n] = f.y;
        }
    }
    __syncthreads();

    int r0 = (t >> 4) * 4;
    int c0 = (t & 15) * 4;
    float acc[4][4] = {};
    #pragma unroll 8
    for (int k = 0; k < 64; ++k) {
        float4 hv = *(const float4*)&ht[k * 68 + r0];
        float4 wv = *(const float4*)&Wt[k * 68 + c0];
        acc[0][0] = fmaf(hv.x, wv.x, acc[0][0]);
        acc[0][1] = fmaf(hv.x, wv.y, acc[0][1]);
        acc[0][2] = fmaf(hv.x, wv.z, acc[0][2]);
        acc[0][3] = fmaf(hv.x, wv.w, acc[0][3]);
        acc[1][0] = fmaf(hv.y, wv.x, acc[1][0]);
        acc[1][1] = fmaf(hv.y, wv.y, acc[1][1]);
        acc[1][2] = fmaf(hv.y, wv.z, acc[1][2]);
        acc[1][3] = fmaf(hv.y, wv.w, acc[1][3]);
        acc[2][0] = fmaf(hv.z, wv.x, acc[2][0]);
        acc[2][1] = fmaf(hv.z, wv.y, acc[2][1]);
        acc[2][2] = fmaf(hv.z, wv.z, acc[2][2]);
        acc[2][3] = fmaf(hv.z, wv.w, acc[2][3]);
        acc[3][0] = fmaf(hv.w, wv.x, acc[3][0]);
        acc[3][1] = fmaf(hv.w, wv.y, acc[3][1]);
        acc[3][2] = fmaf(hv.w, wv.z, acc[3][2]);
        acc[3][3] = fmaf(hv.w, wv.w, acc[3][3]);
    }

    float4 bv = *(const float4*)&b[c0];
    #pragma unroll
    for (int i = 0; i < 4; ++i) {
        int node = nodeBase + r0 + i;
        if (node >= N) continue;
        int base = node * 64 + c0;
        float4 xv = *(const float4*)&x[base];
        float4 pv = *(const float4*)&xp[base];
        float4 o;
        o.x = fmaf(2.f, xv.x, acc[i][0] + bv.x) - pv.x;
        o.y = fmaf(2.f, xv.y, acc[i][1] + bv.y) - pv.y;
        o.z = fmaf(2.f, xv.z, acc[i][2] + bv.z) - pv.z;
        o.w = fmaf(2.f, xv.w, acc[i][3] + bv.w) - pv.w;
        *(float4*)&out[base] = o;
    }
}

extern "C" void kernel_launch(void* const* d_in, const int* in_sizes, int n_in,
                              void* d_out, int out_size, void* d_ws, size_t ws_size,
                              hipStream_t stream) {
    const float* x    = (const float*)d_in[0];
    const float* xpre = (const float*)d_in[1];
    const int*   ei   = (const int*)d_in[2];
    const float* W    = (const float*)d_in[3];
    const float* b    = (const float*)d_in[4];
    float* out = (float*)d_out;

    const int N = in_sizes[0] / CCH;
    const int E = in_sizes[2] / 2;
    const int* src = ei;
    const int* dst = ei + E;

    const int NHB   = (N + HBSZ - 1) / HBSZ;     // 128-node dst blocks (782)
    const int M     = NHB * NBLK;                // count-matrix size (~100k)
    const int chunk = (E + NBLK - 1) / NBLK;
    const int NB2   = (M + 1023) / 1024;         // scan1 blocks

    // workspace partition (256B aligned)
    char* p = (char*)d_ws;
    auto alloc = [&](size_t bytes) -> char* {
        char* r = p;
        p += (bytes + 255) & ~(size_t)255;
        return r;
    };
    int*      cntmat = (int*)alloc((size_t)M * 4);
    int*      part   = (int*)alloc((size_t)M * 4);
    int*      bsum   = (int*)alloc((size_t)NB2 * 4);
    unsigned* brec   = (unsigned*)alloc((size_t)E * 4);
    unsigned* brec2  = (unsigned*)alloc((size_t)E * 4);
    float*    dinv   = (float*)alloc((size_t)N * 4);
    float*    dinv2  = (float*)alloc((size_t)N * 4);
    __half*   xh     = (__half*)alloc((size_t)N * CCH * 2);
    __half*   g0     = (__half*)alloc((size_t)N * CCH * 2);
    __half*   g1     = (__half*)alloc((size_t)N * CCH * 2);

    countA<<<NBLK, 256, 0, stream>>>(dst, cntmat, E, chunk, NHB);
    scan1 <<<NB2, 256, 0, stream>>>(cntmat, part, bsum, M);
    scan2 <<<1, 256, 0, stream>>>(bsum, NB2);
    partA <<<NBLK, 256, 0, stream>>>(src, dst, part, bsum, brec, E, chunk, NHB);
    buildB<<<NHB, 256, 0, stream>>>(brec, part, bsum, brec2, dinv, dinv2,
                                    x, xh, N, NHB, E);

    prop_kernel<<<NHB, 256, 0, stream>>>(xh, g0, brec2, part, bsum, dinv2, N, NHB, E);
    prop_kernel<<<NHB, 256, 0, stream>>>(g0, g1, brec2, part, bsum, dinv2, N, NHB, E);
    prop_kernel<<<NHB, 256, 0, stream>>>(g1, g0, brec2, part, bsum, dinv2, N, NHB, E);
    prop_kernel<<<NHB, 256, 0, stream>>>(g0, g1, brec2, part, bsum, dinv,  N, NHB, E);

    final_kernel<<<(N + 63) / 64, 256, 0, stream>>>(g1, x, xpre, W, b, out, N);
}